// Round 2
// baseline (442.333 us; speedup 1.0000x reference)
//
#include <hip/hip_runtime.h>

typedef unsigned short u16;
typedef __attribute__((ext_vector_type(8))) short bf16x8;
typedef __attribute__((ext_vector_type(4))) float f32x4;

__device__ __forceinline__ float bf2f(u16 u){
  union { unsigned int i; float f; } v; v.i = ((unsigned int)u) << 16; return v.f;
}
__device__ __forceinline__ u16 f2bf(float f){
  union { float f; unsigned int i; } v; v.f = f;
  unsigned int i = v.i;
  return (u16)((i + 0x7fffu + ((i >> 16) & 1u)) >> 16);
}
// dtype-adaptive input load: flag=1 -> f32 buffer, flag=0 -> bf16 buffer
__device__ __forceinline__ float ldin(const void* p, int i, int f){
  return f ? ((const float*)p)[i] : bf2f(((const u16*)p)[i]);
}

// ---------------------------------------------------------------------------
// Kernel S: sniff input dtype from msa_act's first 256 words.
//  f32 (bf16-quantized): low 16 bits of each word are 0.
//  bf16-packed: low u16 decodes as bf16 with exponent in the N(0,1) range.
//  raw f32: neither -> treat as f32.
// ---------------------------------------------------------------------------
__global__ void k_sniff(const unsigned int* __restrict__ msa_w, int* __restrict__ flag)
{
  if (threadIdx.x == 0 && blockIdx.x == 0) {
    int lo0 = 0, expok = 0;
    for (int i = 0; i < 256; ++i) {
      unsigned int w = msa_w[i];
      if ((w & 0xffffu) == 0u) lo0++;
      unsigned int e = (w >> 7) & 0xffu;   // low u16 as bf16: exponent field
      if (e >= 110u && e <= 140u) expok++;
    }
    *flag = (lo0 > 200) ? 1 : ((expok > 200) ? 0 : 1);
  }
}

// ---------------------------------------------------------------------------
// Kernel 0: transpose the 5 weight matrices into bf16 (wq,wk,wv,wg:
// [256c][256hd] -> [col][c]; wo: [256hd][256n] -> [n][hd]).
// ---------------------------------------------------------------------------
__global__ __launch_bounds__(256) void k_transpose(
    const void* __restrict__ wq, const void* __restrict__ wk,
    const void* __restrict__ wv, const void* __restrict__ wg,
    const void* __restrict__ wo, const int* __restrict__ flagp,
    u16* __restrict__ Wt, u16* __restrict__ wot)
{
  const int flag = *flagp;
  int idx = blockIdx.x * 256 + threadIdx.x;     // 0..327679
  int mat = idx >> 16;                          // 0..4
  int col = (idx >> 8) & 255;
  int c   = idx & 255;
  const void* src = (mat == 0) ? wq : (mat == 1) ? wk : (mat == 2) ? wv
                  : (mat == 3) ? wg : wo;
  u16 v = f2bf(ldin(src, c * 256 + col, flag));
  if (idx < 262144) Wt[idx] = v;
  else              wot[idx - 262144] = v;
}

// ---------------------------------------------------------------------------
// Kernel 1: pair LayerNorm + z[h][q][k] = sum_c LN(pair)[q,k,c] * w2d[c,h]
// ---------------------------------------------------------------------------
__global__ __launch_bounds__(256) void k_pair_z(
    const void* __restrict__ pair, const void* __restrict__ png,
    const void* __restrict__ pnb, const void* __restrict__ w2d,
    const int* __restrict__ flagp, float* __restrict__ z)
{
  const int flag = *flagp;
  int wave = threadIdx.x >> 6, lane = threadIdx.x & 63;
  int row = blockIdx.x * 4 + wave;              // 0..65535  (q*256+k)
  float x0 = ldin(pair, row * 128 + lane, flag);
  float x1 = ldin(pair, row * 128 + lane + 64, flag);
  float s = x0 + x1, sq = x0 * x0 + x1 * x1;
  #pragma unroll
  for (int off = 1; off < 64; off <<= 1) {
    s  += __shfl_xor(s,  off, 64);
    sq += __shfl_xor(sq, off, 64);
  }
  float mu = s * (1.f / 128.f);
  float var = sq * (1.f / 128.f) - mu * mu;
  float rs = rsqrtf(var + 1e-5f);
  float n0 = (x0 - mu) * rs * ldin(png, lane, flag)      + ldin(pnb, lane, flag);
  float n1 = (x1 - mu) * rs * ldin(png, lane + 64, flag) + ldin(pnb, lane + 64, flag);
  float outv = 0.f;
  #pragma unroll
  for (int h = 0; h < 8; ++h) {
    float part = n0 * ldin(w2d, lane * 8 + h, flag)
               + n1 * ldin(w2d, (lane + 64) * 8 + h, flag);
    #pragma unroll
    for (int off = 1; off < 64; off <<= 1) part += __shfl_xor(part, off, 64);
    if (lane == h) outv = part;
  }
  if (lane < 8) z[lane * 65536 + row] = outv;
}

// ---------------------------------------------------------------------------
// Kernel 2: msa LayerNorm row stats (mean, rsqrt(var+eps)) per (s,i) row.
// ---------------------------------------------------------------------------
__global__ __launch_bounds__(256) void k_msa_stats(
    const void* __restrict__ msa, const int* __restrict__ flagp,
    float2* __restrict__ stats)
{
  const int flag = *flagp;
  int wave = threadIdx.x >> 6, lane = threadIdx.x & 63;
  int row = blockIdx.x * 4 + wave;              // 0..32767
  float s = 0.f, sq = 0.f;
  #pragma unroll
  for (int j = 0; j < 4; ++j) {
    float x = ldin(msa, row * 256 + lane + 64 * j, flag);
    s += x; sq += x * x;
  }
  #pragma unroll
  for (int off = 1; off < 64; off <<= 1) {
    s  += __shfl_xor(s,  off, 64);
    sq += __shfl_xor(sq, off, 64);
  }
  float mu = s * (1.f / 256.f);
  float var = sq * (1.f / 256.f) - mu * mu;
  if (lane == 0) stats[row] = make_float2(mu, rsqrtf(var + 1e-5f));
}

// ---------------------------------------------------------------------------
// Kernel 3: fused LN + QKVG projection GEMM. M=32768 (s*256+i), N=1024
// (q|k|v|g each 256 = h*32+d), K=256. 128x128 tile, 4 waves 64x64,
// mfma_f32_16x16x32_bf16. Epilogue scatters to attention-friendly layouts.
// ---------------------------------------------------------------------------
__global__ __launch_bounds__(256) void k_qkvg(
    const void* __restrict__ msa, const float2* __restrict__ stats,
    const void* __restrict__ qng, const void* __restrict__ qnb,
    const u16* __restrict__ Wt, const void* __restrict__ bg,
    const int* __restrict__ flagp,
    u16* __restrict__ q_ws, u16* __restrict__ k_ws,
    u16* __restrict__ v_ws, u16* __restrict__ g_ws)
{
  __shared__ u16 As[128 * 32];
  __shared__ u16 Bs[128 * 32];
  const int flag = *flagp;
  const int t = threadIdx.x, lane = t & 63, wave = t >> 6;
  const int wm = (wave >> 1) * 64, wn = (wave & 1) * 64;
  const int rowBase = blockIdx.x * 128;
  const int colBase = blockIdx.y * 128;
  const int sr = t >> 1, sc = (t & 1) * 16;
  const int g = lane >> 4, l15 = lane & 15;
  f32x4 acc[4][4];
  f32x4 zero = {0.f, 0.f, 0.f, 0.f};
  #pragma unroll
  for (int i = 0; i < 4; ++i)
    #pragma unroll
    for (int j = 0; j < 4; ++j) acc[i][j] = zero;
  const int grow = rowBase + sr;
  const float2 st = stats[grow];

  for (int kb = 0; kb < 256; kb += 32) {
    __syncthreads();
    {
      float xv[16];
      if (flag) {
        const float* mF = (const float*)msa + grow * 256 + kb + sc;
        #pragma unroll
        for (int j = 0; j < 4; ++j) {
          float4 f4 = *(const float4*)(mF + 4 * j);
          xv[4*j] = f4.x; xv[4*j+1] = f4.y; xv[4*j+2] = f4.z; xv[4*j+3] = f4.w;
        }
      } else {
        const u16* mB = (const u16*)msa + grow * 256 + kb + sc;
        uint4 u0 = *(const uint4*)mB;
        uint4 u1 = *(const uint4*)(mB + 8);
        const u16* x0 = (const u16*)&u0; const u16* x1 = (const u16*)&u1;
        #pragma unroll
        for (int j = 0; j < 8; ++j) { xv[j] = bf2f(x0[j]); xv[8+j] = bf2f(x1[j]); }
      }
      u16 outp[16];
      #pragma unroll
      for (int j = 0; j < 16; ++j)
        outp[j] = f2bf((xv[j] - st.x) * st.y * ldin(qng, kb + sc + j, flag)
                       + ldin(qnb, kb + sc + j, flag));
      *(uint4*)(As + sr * 32 + sc)     = *(const uint4*)outp;
      *(uint4*)(As + sr * 32 + sc + 8) = *(const uint4*)(outp + 8);
      uint4 w0 = *(const uint4*)(Wt + (colBase + sr) * 256 + kb + sc);
      uint4 w1 = *(const uint4*)(Wt + (colBase + sr) * 256 + kb + sc + 8);
      *(uint4*)(Bs + sr * 32 + sc)     = w0;
      *(uint4*)(Bs + sr * 32 + sc + 8) = w1;
    }
    __syncthreads();
    bf16x8 a[4], b[4];
    #pragma unroll
    for (int mt = 0; mt < 4; ++mt)
      a[mt] = *(const bf16x8*)(As + (wm + mt * 16 + l15) * 32 + g * 8);
    #pragma unroll
    for (int nt = 0; nt < 4; ++nt)
      b[nt] = *(const bf16x8*)(Bs + (wn + nt * 16 + l15) * 32 + g * 8);
    #pragma unroll
    for (int mt = 0; mt < 4; ++mt)
      #pragma unroll
      for (int nt = 0; nt < 4; ++nt)
        acc[mt][nt] = __builtin_amdgcn_mfma_f32_16x16x32_bf16(a[mt], b[nt], acc[mt][nt], 0, 0, 0);
  }

  const int t4 = colBase >> 8;  // uniform per block: 0=q 1=k 2=v 3=g
  const float scale = 0.17677669529663687f;  // 1/sqrt(32)
  #pragma unroll
  for (int mt = 0; mt < 4; ++mt)
    #pragma unroll
    for (int nt = 0; nt < 4; ++nt)
      #pragma unroll
      for (int r = 0; r < 4; ++r) {
        int row = rowBase + wm + mt * 16 + g * 4 + r;   // s*256+i
        int col = colBase + wn + nt * 16 + l15;         // 0..1023
        int s_ = row >> 8, ii = row & 255;
        int inner = col & 255, hh = inner >> 5, dd = inner & 31;
        float v = acc[mt][nt][r];
        if (t4 == 0)      q_ws[((s_ * 8 + hh) * 256 + ii) * 32 + dd] = f2bf(v * scale);
        else if (t4 == 1) k_ws[((s_ * 8 + hh) * 256 + ii) * 32 + dd] = f2bf(v);
        else if (t4 == 2) v_ws[((s_ * 8 + hh) * 32 + dd) * 256 + ii] = f2bf(v);
        else {
          float gv = v + ldin(bg, inner, flag);
          gv = 1.0f / (1.0f + __expf(-gv));
          g_ws[row * 256 + inner] = f2bf(gv);
        }
      }
}

// ---------------------------------------------------------------------------
// Kernel 4: attention per (s,h). QK^T via MFMA, bias+mask, 16-lane-shuffle
// softmax, P C-layout -> A-layout via wave-private LDS chunk, PV via MFMA.
// ---------------------------------------------------------------------------
__global__ __launch_bounds__(256) void k_attn(
    const u16* __restrict__ q_ws, const u16* __restrict__ k_ws,
    const u16* __restrict__ v_ws, const float* __restrict__ z,
    const void* __restrict__ mask, const u16* __restrict__ g_ws,
    const int* __restrict__ flagp, u16* __restrict__ og_ws)
{
  __shared__ u16 Ks[256 * 32];      // [k][d]
  __shared__ u16 Vts[32 * 264];     // [d][k], row pad 256->264
  __shared__ u16 Pb[4 * 16 * 40];   // per-wave [16 q][32 k-chunk], pad 32->40
  const int flag = *flagp;
  const int t = threadIdx.x, lane = t & 63, wave = t >> 6;
  const int sh = blockIdx.x;        // s*8+h
  const int s_ = sh >> 3, h = sh & 7;

  {
    const uint4* srcK = (const uint4*)(k_ws + sh * 8192);
    uint4* dstK = (uint4*)Ks;
    #pragma unroll
    for (int j = 0; j < 4; ++j) dstK[t + 256 * j] = srcK[t + 256 * j];
    int row = t >> 3, seg = t & 7;
    const uint4* srcV = (const uint4*)(v_ws + sh * 8192 + row * 256 + seg * 32);
    uint4* dstV = (uint4*)(Vts + row * 264 + seg * 32);
    #pragma unroll
    for (int j = 0; j < 4; ++j) dstV[j] = srcV[j];
  }
  __syncthreads();

  const int g = lane >> 4, l15 = lane & 15;
  const u16* qb = q_ws + sh * 8192;
  u16* pb = Pb + wave * 640;
  f32x4 zero = {0.f, 0.f, 0.f, 0.f};

  for (int qt = 0; qt < 4; ++qt) {
    const int qbase = wave * 64 + qt * 16;
    bf16x8 aq = *(const bf16x8*)(qb + (qbase + l15) * 32 + g * 8);
    f32x4 S[16];
    #pragma unroll
    for (int kt = 0; kt < 16; ++kt) {
      bf16x8 bk = *(const bf16x8*)(Ks + (kt * 16 + l15) * 32 + g * 8);
      S[kt] = __builtin_amdgcn_mfma_f32_16x16x32_bf16(aq, bk, zero, 0, 0, 0);
    }
    float mx[4] = {-1e30f, -1e30f, -1e30f, -1e30f};
    #pragma unroll
    for (int kt = 0; kt < 16; ++kt) {
      int k = kt * 16 + l15;
      float mb = 1e9f * (ldin(mask, s_ * 256 + k, flag) - 1.0f);
      const float* zp = z + h * 65536 + (qbase + g * 4) * 256 + k;
      #pragma unroll
      for (int r = 0; r < 4; ++r) {
        float val = S[kt][r] + mb + zp[r * 256];
        S[kt][r] = val;
        mx[r] = fmaxf(mx[r], val);
      }
    }
    #pragma unroll
    for (int r = 0; r < 4; ++r)
      #pragma unroll
      for (int off = 1; off < 16; off <<= 1)
        mx[r] = fmaxf(mx[r], __shfl_xor(mx[r], off, 64));
    float sm[4] = {0.f, 0.f, 0.f, 0.f};
    #pragma unroll
    for (int kt = 0; kt < 16; ++kt)
      #pragma unroll
      for (int r = 0; r < 4; ++r) {
        float p = __expf(S[kt][r] - mx[r]);
        S[kt][r] = p;
        sm[r] += p;
      }
    #pragma unroll
    for (int r = 0; r < 4; ++r)
      #pragma unroll
      for (int off = 1; off < 16; off <<= 1)
        sm[r] += __shfl_xor(sm[r], off, 64);

    f32x4 O0 = zero, O1 = zero;
    #pragma unroll
    for (int kc = 0; kc < 8; ++kc) {
      asm volatile("s_waitcnt lgkmcnt(0)" ::: "memory");
      #pragma unroll
      for (int half = 0; half < 2; ++half) {
        int kt = kc * 2 + half;
        #pragma unroll
        for (int r = 0; r < 4; ++r)
          pb[(g * 4 + r) * 40 + half * 16 + l15] = f2bf(S[kt][r]);
      }
      asm volatile("s_waitcnt lgkmcnt(0)" ::: "memory");
      bf16x8 ap  = *(const bf16x8*)(pb + l15 * 40 + g * 8);
      bf16x8 bv0 = *(const bf16x8*)(Vts + l15 * 264 + kc * 32 + g * 8);
      bf16x8 bv1 = *(const bf16x8*)(Vts + (16 + l15) * 264 + kc * 32 + g * 8);
      O0 = __builtin_amdgcn_mfma_f32_16x16x32_bf16(ap, bv0, O0, 0, 0, 0);
      O1 = __builtin_amdgcn_mfma_f32_16x16x32_bf16(ap, bv1, O1, 0, 0, 0);
    }
    #pragma unroll
    for (int r = 0; r < 4; ++r) {
      float inv = 1.0f / sm[r];
      int qq = qbase + g * 4 + r;
      int base = (s_ * 256 + qq) * 256 + h * 32;
      float o0 = O0[r] * inv * bf2f(g_ws[base + l15]);
      float o1 = O1[r] * inv * bf2f(g_ws[base + 16 + l15]);
      og_ws[base + l15]      = f2bf(o0);
      og_ws[base + 16 + l15] = f2bf(o1);
    }
  }
}

// ---------------------------------------------------------------------------
// Kernel 5: output projection GEMM. M=32768, N=256, K=256 (h*32+d). +bo.
// ---------------------------------------------------------------------------
__global__ __launch_bounds__(256) void k_outproj(
    const u16* __restrict__ og, const u16* __restrict__ wot,
    const void* __restrict__ bo, const int* __restrict__ flagp,
    void* __restrict__ outv)
{
  __shared__ u16 As[128 * 32];
  __shared__ u16 Bs[128 * 32];
  const int flag = *flagp;
  const int t = threadIdx.x, lane = t & 63, wave = t >> 6;
  const int wm = (wave >> 1) * 64, wn = (wave & 1) * 64;
  const int rowBase = blockIdx.x * 128;
  const int colBase = blockIdx.y * 128;
  const int sr = t >> 1, sc = (t & 1) * 16;
  const int g = lane >> 4, l15 = lane & 15;
  f32x4 acc[4][4];
  f32x4 zero = {0.f, 0.f, 0.f, 0.f};
  #pragma unroll
  for (int i = 0; i < 4; ++i)
    #pragma unroll
    for (int j = 0; j < 4; ++j) acc[i][j] = zero;
  const int grow = rowBase + sr;

  for (int kb = 0; kb < 256; kb += 32) {
    __syncthreads();
    {
      uint4 a0 = *(const uint4*)(og + grow * 256 + kb + sc);
      uint4 a1 = *(const uint4*)(og + grow * 256 + kb + sc + 8);
      *(uint4*)(As + sr * 32 + sc)     = a0;
      *(uint4*)(As + sr * 32 + sc + 8) = a1;
      uint4 w0 = *(const uint4*)(wot + (colBase + sr) * 256 + kb + sc);
      uint4 w1 = *(const uint4*)(wot + (colBase + sr) * 256 + kb + sc + 8);
      *(uint4*)(Bs + sr * 32 + sc)     = w0;
      *(uint4*)(Bs + sr * 32 + sc + 8) = w1;
    }
    __syncthreads();
    bf16x8 a[4], b[4];
    #pragma unroll
    for (int mt = 0; mt < 4; ++mt)
      a[mt] = *(const bf16x8*)(As + (wm + mt * 16 + l15) * 32 + g * 8);
    #pragma unroll
    for (int nt = 0; nt < 4; ++nt)
      b[nt] = *(const bf16x8*)(Bs + (wn + nt * 16 + l15) * 32 + g * 8);
    #pragma unroll
    for (int mt = 0; mt < 4; ++mt)
      #pragma unroll
      for (int nt = 0; nt < 4; ++nt)
        acc[mt][nt] = __builtin_amdgcn_mfma_f32_16x16x32_bf16(a[mt], b[nt], acc[mt][nt], 0, 0, 0);
  }
  #pragma unroll
  for (int mt = 0; mt < 4; ++mt)
    #pragma unroll
    for (int nt = 0; nt < 4; ++nt)
      #pragma unroll
      for (int r = 0; r < 4; ++r) {
        int row = rowBase + wm + mt * 16 + g * 4 + r;
        int col = colBase + wn + nt * 16 + l15;
        float val = acc[mt][nt][r] + ldin(bo, col, flag);
        if (flag) ((float*)outv)[row * 256 + col] = val;
        else      ((u16*)outv)[row * 256 + col]   = f2bf(val);
      }
}

// ---------------------------------------------------------------------------
extern "C" void kernel_launch(void* const* d_in, const int* in_sizes, int n_in,
                              void* d_out, int out_size, void* d_ws, size_t ws_size,
                              hipStream_t stream)
{
  const void* msa  = d_in[0];
  const void* pair = d_in[1];
  const void* mask = d_in[2];
  const void* qng  = d_in[3];
  const void* qnb  = d_in[4];
  const void* png  = d_in[5];
  const void* pnb  = d_in[6];
  const void* w2d  = d_in[7];
  const void* wq   = d_in[8];
  const void* wk   = d_in[9];
  const void* wv   = d_in[10];
  const void* wg   = d_in[11];
  const void* bg   = d_in[12];
  const void* wo   = d_in[13];
  const void* bo   = d_in[14];

  char* ws = (char*)d_ws;
  float*  z     = (float*)(ws + 0);             // 2,097,152 B
  float2* stats = (float2*)(ws + 2097152);      //   262,144 B
  u16* Wt    = (u16*)(ws + 2359296);            //   524,288 B
  u16* wot   = (u16*)(ws + 2883584);            //   131,072 B
  u16* q_ws  = (u16*)(ws + 3014656);            // 16,777,216 B each
  u16* k_ws  = (u16*)(ws + 19791872);
  u16* v_ws  = (u16*)(ws + 36569088);
  u16* g_ws  = (u16*)(ws + 53346304);
  u16* og_ws = (u16*)(ws + 70123520);           // ends 86,900,736
  int* flag  = (int*)(ws + 86900736);           // 4 B

  hipLaunchKernelGGL(k_sniff, dim3(1), dim3(64), 0, stream,
                     (const unsigned int*)msa, flag);
  hipLaunchKernelGGL(k_transpose, dim3(1280), dim3(256), 0, stream,
                     wq, wk, wv, wg, wo, flag, Wt, wot);
  hipLaunchKernelGGL(k_pair_z, dim3(16384), dim3(256), 0, stream,
                     pair, png, pnb, w2d, flag, z);
  hipLaunchKernelGGL(k_msa_stats, dim3(8192), dim3(256), 0, stream,
                     msa, flag, stats);
  hipLaunchKernelGGL(k_qkvg, dim3(256, 8), dim3(256), 0, stream,
                     msa, stats, qng, qnb, Wt, bg, flag, q_ws, k_ws, v_ws, g_ws);
  hipLaunchKernelGGL(k_attn, dim3(1024), dim3(256), 0, stream,
                     q_ws, k_ws, v_ws, z, mask, g_ws, flag, og_ws);
  hipLaunchKernelGGL(k_outproj, dim3(256, 2), dim3(256), 0, stream,
                     og_ws, wot, bo, flag, d_out);
}

// Round 3
// 312.633 us; speedup vs baseline: 1.4149x; 1.4149x over previous
//
#include <hip/hip_runtime.h>

typedef unsigned short u16;
typedef __attribute__((ext_vector_type(8))) short bf16x8;
typedef __attribute__((ext_vector_type(4))) float f32x4;

__device__ __forceinline__ float bf2f(u16 u){
  union { unsigned int i; float f; } v; v.i = ((unsigned int)u) << 16; return v.f;
}
__device__ __forceinline__ u16 f2bf(float f){
  union { float f; unsigned int i; } v; v.f = f;
  unsigned int i = v.i;
  return (u16)((i + 0x7fffu + ((i >> 16) & 1u)) >> 16);
}
// dtype-adaptive input load: flag=1 -> f32 buffer, flag=0 -> bf16 buffer
__device__ __forceinline__ float ldin(const void* p, int i, int f){
  return f ? ((const float*)p)[i] : bf2f(((const u16*)p)[i]);
}
// load 8 consecutive input elements (idx must be 8-aligned)
__device__ __forceinline__ void ld8(const void* p, int idx, int flag, float* out){
  if (flag) {
    const float* q = (const float*)p + idx;
    float4 a = *(const float4*)q, b = *(const float4*)(q + 4);
    out[0]=a.x; out[1]=a.y; out[2]=a.z; out[3]=a.w;
    out[4]=b.x; out[5]=b.y; out[6]=b.z; out[7]=b.w;
  } else {
    const u16* q = (const u16*)p + idx;
    uint4 u = *(const uint4*)q;
    const u16* h = (const u16*)&u;
    #pragma unroll
    for (int j = 0; j < 8; ++j) out[j] = bf2f(h[j]);
  }
}
// async global->LDS, 16B per lane; LDS dest = wave-uniform base + lane*16
__device__ __forceinline__ void gload16(const u16* g, u16* l){
  __builtin_amdgcn_global_load_lds(
      (const __attribute__((address_space(1))) void*)g,
      (__attribute__((address_space(3))) void*)l, 16, 0, 0);
}

// ---------------------------------------------------------------------------
// Kernel S: sniff input dtype from msa_act's first 256 words (64 lanes x 4).
// ---------------------------------------------------------------------------
__global__ void k_sniff(const unsigned int* __restrict__ msa_w, int* __restrict__ flag)
{
  int lane = threadIdx.x & 63;
  int lo0 = 0, expok = 0;
  #pragma unroll
  for (int j = 0; j < 4; ++j) {
    unsigned int w = msa_w[lane * 4 + j];
    if ((w & 0xffffu) == 0u) lo0++;
    unsigned int e = (w >> 7) & 0xffu;
    if (e >= 110u && e <= 140u) expok++;
  }
  #pragma unroll
  for (int off = 1; off < 64; off <<= 1) {
    lo0   += __shfl_xor(lo0,   off, 64);
    expok += __shfl_xor(expok, off, 64);
  }
  if (lane == 0 && blockIdx.x == 0)
    *flag = (lo0 > 200) ? 1 : ((expok > 200) ? 0 : 1);
}

// ---------------------------------------------------------------------------
// Kernel 0: transpose the 5 weight matrices into bf16.
// ---------------------------------------------------------------------------
__global__ __launch_bounds__(256) void k_transpose(
    const void* __restrict__ wq, const void* __restrict__ wk,
    const void* __restrict__ wv, const void* __restrict__ wg,
    const void* __restrict__ wo, const int* __restrict__ flagp,
    u16* __restrict__ Wt, u16* __restrict__ wot)
{
  const int flag = *flagp;
  int idx = blockIdx.x * 256 + threadIdx.x;     // 0..327679
  int mat = idx >> 16;
  int col = (idx >> 8) & 255;
  int c   = idx & 255;
  const void* src = (mat == 0) ? wq : (mat == 1) ? wk : (mat == 2) ? wv
                  : (mat == 3) ? wg : wo;
  u16 v = f2bf(ldin(src, c * 256 + col, flag));
  if (idx < 262144) Wt[idx] = v;
  else              wot[idx - 262144] = v;
}

// ---------------------------------------------------------------------------
// Kernel 1: pair LayerNorm + z[h][q*256+k]. 16 lanes per row (8 ch/lane):
// 4 rows/wave, 16 rows/block -> 4096 blocks. ~40 shuffles per 4 rows.
// ---------------------------------------------------------------------------
__global__ __launch_bounds__(256) void k_pair_z(
    const void* __restrict__ pair, const void* __restrict__ png,
    const void* __restrict__ pnb, const void* __restrict__ w2d,
    const int* __restrict__ flagp, float* __restrict__ z)
{
  const int flag = *flagp;
  const int t = threadIdx.x, lane = t & 63, wave = t >> 6;
  const int sub = lane >> 4, l15 = lane & 15;
  const int row = blockIdx.x * 16 + wave * 4 + sub;   // q*256+k
  const int c0 = l15 * 8;
  float x[8];
  ld8(pair, row * 128 + c0, flag, x);
  float s = 0.f, sq = 0.f;
  #pragma unroll
  for (int j = 0; j < 8; ++j) { s += x[j]; sq += x[j] * x[j]; }
  #pragma unroll
  for (int off = 1; off < 16; off <<= 1) {
    s  += __shfl_xor(s,  off, 64);
    sq += __shfl_xor(sq, off, 64);
  }
  float mu = s * (1.f / 128.f);
  float var = sq * (1.f / 128.f) - mu * mu;
  float rs = rsqrtf(var + 1e-5f);
  float n[8];
  #pragma unroll
  for (int j = 0; j < 8; ++j)
    n[j] = (x[j] - mu) * rs * ldin(png, c0 + j, flag) + ldin(pnb, c0 + j, flag);
  float part[8] = {0.f,0.f,0.f,0.f,0.f,0.f,0.f,0.f};
  #pragma unroll
  for (int j = 0; j < 8; ++j) {
    float w[8];
    ld8(w2d, (c0 + j) * 8, flag, w);
    #pragma unroll
    for (int h = 0; h < 8; ++h) part[h] += n[j] * w[h];
  }
  #pragma unroll
  for (int h = 0; h < 8; ++h)
    #pragma unroll
    for (int off = 1; off < 16; off <<= 1)
      part[h] += __shfl_xor(part[h], off, 64);
  if (l15 < 8) {
    float outv = part[0];
    #pragma unroll
    for (int h = 1; h < 8; ++h) if (l15 == h) outv = part[h];
    z[l15 * 65536 + row] = outv;
  }
}

// ---------------------------------------------------------------------------
// Kernel 2: msa LayerNorm fully applied -> m_bf16 (bf16, row-major 256).
// Wave per row, 4 contiguous ch/lane.
// ---------------------------------------------------------------------------
__global__ __launch_bounds__(256) void k_msa_ln(
    const void* __restrict__ msa, const void* __restrict__ qng,
    const void* __restrict__ qnb, const int* __restrict__ flagp,
    u16* __restrict__ m_bf)
{
  const int flag = *flagp;
  int wave = threadIdx.x >> 6, lane = threadIdx.x & 63;
  int row = blockIdx.x * 4 + wave;              // 0..32767
  float x[4];
  if (flag) {
    float4 f4 = *((const float4*)msa + row * 64 + lane);
    x[0]=f4.x; x[1]=f4.y; x[2]=f4.z; x[3]=f4.w;
  } else {
    uint2 u = *((const uint2*)msa + row * 64 + lane);
    const u16* h = (const u16*)&u;
    #pragma unroll
    for (int j = 0; j < 4; ++j) x[j] = bf2f(h[j]);
  }
  float s = 0.f, sq = 0.f;
  #pragma unroll
  for (int j = 0; j < 4; ++j) { s += x[j]; sq += x[j] * x[j]; }
  #pragma unroll
  for (int off = 1; off < 64; off <<= 1) {
    s  += __shfl_xor(s,  off, 64);
    sq += __shfl_xor(sq, off, 64);
  }
  float mu = s * (1.f / 256.f);
  float var = sq * (1.f / 256.f) - mu * mu;
  float rs = rsqrtf(var + 1e-5f);
  u16 o[4];
  #pragma unroll
  for (int j = 0; j < 4; ++j) {
    int c = lane * 4 + j;
    o[j] = f2bf((x[j] - mu) * rs * ldin(qng, c, flag) + ldin(qnb, c, flag));
  }
  *((uint2*)m_bf + row * 64 + lane) = *(const uint2*)o;
}

// ---------------------------------------------------------------------------
// Kernel 3: QKVG projection GEMM (A = pre-normalized bf16 msa). m97-style:
// global_load_lds width-16 staging, 128x128 tile, BK=32, 4 waves 64x64.
// ---------------------------------------------------------------------------
__global__ __launch_bounds__(256) void k_qkvg(
    const u16* __restrict__ m_bf, const u16* __restrict__ Wt,
    const void* __restrict__ bg, const int* __restrict__ flagp,
    u16* __restrict__ q_ws, u16* __restrict__ k_ws,
    u16* __restrict__ v_ws, u16* __restrict__ g_ws)
{
  __shared__ u16 As[128 * 32];
  __shared__ u16 Bs[128 * 32];
  const int flag = *flagp;
  const int t = threadIdx.x, lane = t & 63, wave = t >> 6;
  const int wm = (wave >> 1) * 64, wn = (wave & 1) * 64;
  const int rowBase = blockIdx.x * 128;
  const int colBase = blockIdx.y * 128;
  const int g = lane >> 4, l15 = lane & 15;
  // staging: wave covers 32 rows (2 issues x 16 rows); lane -> row/chunk
  const int srow = wave * 32 + (lane >> 2);   // +0 / +16
  const int scol = (lane & 3) * 8;
  const u16* gA = m_bf + (rowBase + srow) * 256 + scol;
  const u16* gB = Wt   + (colBase + srow) * 256 + scol;
  u16* lA = As + wave * 32 * 32;              // wave-uniform LDS bases
  u16* lB = Bs + wave * 32 * 32;

  f32x4 acc[4][4];
  f32x4 zero = {0.f, 0.f, 0.f, 0.f};
  #pragma unroll
  for (int i = 0; i < 4; ++i)
    #pragma unroll
    for (int j = 0; j < 4; ++j) acc[i][j] = zero;

  for (int kb = 0; kb < 256; kb += 32) {
    __syncthreads();
    gload16(gA + kb,            lA);
    gload16(gA + kb + 16 * 256, lA + 16 * 32);
    gload16(gB + kb,            lB);
    gload16(gB + kb + 16 * 256, lB + 16 * 32);
    __syncthreads();
    bf16x8 a[4], b[4];
    #pragma unroll
    for (int mt = 0; mt < 4; ++mt)
      a[mt] = *(const bf16x8*)(As + (wm + mt * 16 + l15) * 32 + g * 8);
    #pragma unroll
    for (int nt = 0; nt < 4; ++nt)
      b[nt] = *(const bf16x8*)(Bs + (wn + nt * 16 + l15) * 32 + g * 8);
    #pragma unroll
    for (int mt = 0; mt < 4; ++mt)
      #pragma unroll
      for (int nt = 0; nt < 4; ++nt)
        acc[mt][nt] = __builtin_amdgcn_mfma_f32_16x16x32_bf16(a[mt], b[nt], acc[mt][nt], 0, 0, 0);
  }

  const int t4 = colBase >> 8;  // 0=q 1=k 2=v 3=g (uniform per block)
  const float scale = 0.17677669529663687f;  // 1/sqrt(32)
  #pragma unroll
  for (int mt = 0; mt < 4; ++mt)
    #pragma unroll
    for (int nt = 0; nt < 4; ++nt)
      #pragma unroll
      for (int r = 0; r < 4; ++r) {
        int row = rowBase + wm + mt * 16 + g * 4 + r;   // s*256+i
        int col = colBase + wn + nt * 16 + l15;
        int s_ = row >> 8, ii = row & 255;
        int inner = col & 255, hh = inner >> 5, dd = inner & 31;
        float v = acc[mt][nt][r];
        if (t4 == 0)      q_ws[((s_ * 8 + hh) * 256 + ii) * 32 + dd] = f2bf(v * scale);
        else if (t4 == 1) k_ws[((s_ * 8 + hh) * 256 + ii) * 32 + dd] = f2bf(v);
        else if (t4 == 2) v_ws[((s_ * 8 + hh) * 256 + ii) * 32 + dd] = f2bf(v);
        else {
          float gv = v + ldin(bg, inner, flag);
          gv = 1.0f / (1.0f + __expf(-gv));
          g_ws[row * 256 + inner] = f2bf(gv);
        }
      }
}

// ---------------------------------------------------------------------------
// Kernel 4: attention per (s,h). V transposed into LDS during staging.
// ---------------------------------------------------------------------------
__global__ __launch_bounds__(256) void k_attn(
    const u16* __restrict__ q_ws, const u16* __restrict__ k_ws,
    const u16* __restrict__ v_ws, const float* __restrict__ z,
    const void* __restrict__ mask, const u16* __restrict__ g_ws,
    const int* __restrict__ flagp, u16* __restrict__ og_ws)
{
  __shared__ u16 Ks[256 * 32];      // [k][d]
  __shared__ u16 Vts[32 * 264];     // [d][k], row pad 256->264
  __shared__ u16 Pb[4 * 16 * 40];   // per-wave P chunk, pad 32->40
  const int flag = *flagp;
  const int t = threadIdx.x, lane = t & 63, wave = t >> 6;
  const int sh = blockIdx.x;        // s*8+h
  const int s_ = sh >> 3, h = sh & 7;

  {
    const uint4* srcK = (const uint4*)(k_ws + sh * 8192);
    uint4* dstK = (uint4*)Ks;
    #pragma unroll
    for (int j = 0; j < 4; ++j) dstK[t + 256 * j] = srcK[t + 256 * j];
    // V: thread t owns k-row t; transpose into Vts[d][k]
    const u16* sv = v_ws + sh * 8192 + t * 32;
    uint4 v0 = *(const uint4*)sv, v1 = *(const uint4*)(sv + 8);
    const u16* ve = (const u16*)&v0;
    const u16* vo = (const u16*)&v1;
    #pragma unroll
    for (int d = 0; d < 8; ++d) Vts[d * 264 + t] = ve[d];
    #pragma unroll
    for (int d = 0; d < 8; ++d) Vts[(8 + d) * 264 + t] = vo[d];
    const u16* sv2 = sv + 16;
    uint4 v2 = *(const uint4*)sv2, v3 = *(const uint4*)(sv2 + 8);
    const u16* ve2 = (const u16*)&v2;
    const u16* vo2 = (const u16*)&v3;
    #pragma unroll
    for (int d = 0; d < 8; ++d) Vts[(16 + d) * 264 + t] = ve2[d];
    #pragma unroll
    for (int d = 0; d < 8; ++d) Vts[(24 + d) * 264 + t] = vo2[d];
  }
  __syncthreads();

  const int g = lane >> 4, l15 = lane & 15;
  const u16* qb = q_ws + sh * 8192;
  u16* pb = Pb + wave * 640;
  f32x4 zero = {0.f, 0.f, 0.f, 0.f};

  for (int qt = 0; qt < 4; ++qt) {
    const int qbase = wave * 64 + qt * 16;
    bf16x8 aq = *(const bf16x8*)(qb + (qbase + l15) * 32 + g * 8);
    f32x4 S[16];
    #pragma unroll
    for (int kt = 0; kt < 16; ++kt) {
      bf16x8 bk = *(const bf16x8*)(Ks + (kt * 16 + l15) * 32 + g * 8);
      S[kt] = __builtin_amdgcn_mfma_f32_16x16x32_bf16(aq, bk, zero, 0, 0, 0);
    }
    float mx[4] = {-1e30f, -1e30f, -1e30f, -1e30f};
    #pragma unroll
    for (int kt = 0; kt < 16; ++kt) {
      int k = kt * 16 + l15;
      float mb = 1e9f * (ldin(mask, s_ * 256 + k, flag) - 1.0f);
      const float* zp = z + h * 65536 + (qbase + g * 4) * 256 + k;
      #pragma unroll
      for (int r = 0; r < 4; ++r) {
        float val = S[kt][r] + mb + zp[r * 256];
        S[kt][r] = val;
        mx[r] = fmaxf(mx[r], val);
      }
    }
    #pragma unroll
    for (int r = 0; r < 4; ++r)
      #pragma unroll
      for (int off = 1; off < 16; off <<= 1)
        mx[r] = fmaxf(mx[r], __shfl_xor(mx[r], off, 64));
    float sm[4] = {0.f, 0.f, 0.f, 0.f};
    #pragma unroll
    for (int kt = 0; kt < 16; ++kt)
      #pragma unroll
      for (int r = 0; r < 4; ++r) {
        float p = __expf(S[kt][r] - mx[r]);
        S[kt][r] = p;
        sm[r] += p;
      }
    #pragma unroll
    for (int r = 0; r < 4; ++r)
      #pragma unroll
      for (int off = 1; off < 16; off <<= 1)
        sm[r] += __shfl_xor(sm[r], off, 64);

    f32x4 O0 = zero, O1 = zero;
    #pragma unroll
    for (int kc = 0; kc < 8; ++kc) {
      asm volatile("s_waitcnt lgkmcnt(0)" ::: "memory");
      #pragma unroll
      for (int half = 0; half < 2; ++half) {
        int kt = kc * 2 + half;
        #pragma unroll
        for (int r = 0; r < 4; ++r)
          pb[(g * 4 + r) * 40 + half * 16 + l15] = f2bf(S[kt][r]);
      }
      asm volatile("s_waitcnt lgkmcnt(0)" ::: "memory");
      bf16x8 ap  = *(const bf16x8*)(pb + l15 * 40 + g * 8);
      bf16x8 bv0 = *(const bf16x8*)(Vts + l15 * 264 + kc * 32 + g * 8);
      bf16x8 bv1 = *(const bf16x8*)(Vts + (16 + l15) * 264 + kc * 32 + g * 8);
      O0 = __builtin_amdgcn_mfma_f32_16x16x32_bf16(ap, bv0, O0, 0, 0, 0);
      O1 = __builtin_amdgcn_mfma_f32_16x16x32_bf16(ap, bv1, O1, 0, 0, 0);
    }
    #pragma unroll
    for (int r = 0; r < 4; ++r) {
      float inv = 1.0f / sm[r];
      int qq = qbase + g * 4 + r;
      int base = (s_ * 256 + qq) * 256 + h * 32;
      float o0 = O0[r] * inv * bf2f(g_ws[base + l15]);
      float o1 = O1[r] * inv * bf2f(g_ws[base + 16 + l15]);
      og_ws[base + l15]      = f2bf(o0);
      og_ws[base + 16 + l15] = f2bf(o1);
    }
  }
}

// ---------------------------------------------------------------------------
// Kernel 5: output projection GEMM with async staging. M=32768, N=256, K=256.
// ---------------------------------------------------------------------------
__global__ __launch_bounds__(256) void k_outproj(
    const u16* __restrict__ og, const u16* __restrict__ wot,
    const void* __restrict__ bo, const int* __restrict__ flagp,
    void* __restrict__ outv)
{
  __shared__ u16 As[128 * 32];
  __shared__ u16 Bs[128 * 32];
  const int flag = *flagp;
  const int t = threadIdx.x, lane = t & 63, wave = t >> 6;
  const int wm = (wave >> 1) * 64, wn = (wave & 1) * 64;
  const int rowBase = blockIdx.x * 128;
  const int colBase = blockIdx.y * 128;
  const int g = lane >> 4, l15 = lane & 15;
  const int srow = wave * 32 + (lane >> 2);
  const int scol = (lane & 3) * 8;
  const u16* gA = og  + (rowBase + srow) * 256 + scol;
  const u16* gB = wot + (colBase + srow) * 256 + scol;
  u16* lA = As + wave * 32 * 32;
  u16* lB = Bs + wave * 32 * 32;

  f32x4 acc[4][4];
  f32x4 zero = {0.f, 0.f, 0.f, 0.f};
  #pragma unroll
  for (int i = 0; i < 4; ++i)
    #pragma unroll
    for (int j = 0; j < 4; ++j) acc[i][j] = zero;

  for (int kb = 0; kb < 256; kb += 32) {
    __syncthreads();
    gload16(gA + kb,            lA);
    gload16(gA + kb + 16 * 256, lA + 16 * 32);
    gload16(gB + kb,            lB);
    gload16(gB + kb + 16 * 256, lB + 16 * 32);
    __syncthreads();
    bf16x8 a[4], b[4];
    #pragma unroll
    for (int mt = 0; mt < 4; ++mt)
      a[mt] = *(const bf16x8*)(As + (wm + mt * 16 + l15) * 32 + g * 8);
    #pragma unroll
    for (int nt = 0; nt < 4; ++nt)
      b[nt] = *(const bf16x8*)(Bs + (wn + nt * 16 + l15) * 32 + g * 8);
    #pragma unroll
    for (int mt = 0; mt < 4; ++mt)
      #pragma unroll
      for (int nt = 0; nt < 4; ++nt)
        acc[mt][nt] = __builtin_amdgcn_mfma_f32_16x16x32_bf16(a[mt], b[nt], acc[mt][nt], 0, 0, 0);
  }
  #pragma unroll
  for (int mt = 0; mt < 4; ++mt)
    #pragma unroll
    for (int nt = 0; nt < 4; ++nt)
      #pragma unroll
      for (int r = 0; r < 4; ++r) {
        int row = rowBase + wm + mt * 16 + g * 4 + r;
        int col = colBase + wn + nt * 16 + l15;
        float val = acc[mt][nt][r] + ldin(bo, col, flag);
        if (flag) ((float*)outv)[row * 256 + col] = val;
        else      ((u16*)outv)[row * 256 + col]   = f2bf(val);
      }
}

// ---------------------------------------------------------------------------
extern "C" void kernel_launch(void* const* d_in, const int* in_sizes, int n_in,
                              void* d_out, int out_size, void* d_ws, size_t ws_size,
                              hipStream_t stream)
{
  const void* msa  = d_in[0];
  const void* pair = d_in[1];
  const void* mask = d_in[2];
  const void* qng  = d_in[3];
  const void* qnb  = d_in[4];
  const void* png  = d_in[5];
  const void* pnb  = d_in[6];
  const void* w2d  = d_in[7];
  const void* wq   = d_in[8];
  const void* wk   = d_in[9];
  const void* wv   = d_in[10];
  const void* wg   = d_in[11];
  const void* bg   = d_in[12];
  const void* wo   = d_in[13];
  const void* bo   = d_in[14];

  char* ws = (char*)d_ws;
  float* z   = (float*)(ws + 0);                //  2,097,152
  u16* Wt    = (u16*)(ws + 2097152);            //    524,288
  u16* wot   = (u16*)(ws + 2621440);            //    131,072
  int* flag  = (int*)(ws + 2752512);            //        256 (aligned slot)
  u16* m_bf  = (u16*)(ws + 2752768);            // 16,777,216 (aliased w/ og_ws)
  u16* og_ws = m_bf;                            //   (m_bf dead after k_qkvg)
  u16* q_ws  = (u16*)(ws + 19529984);           // 16,777,216
  u16* k_ws  = (u16*)(ws + 36307200);           // 16,777,216
  u16* v_ws  = (u16*)(ws + 53084416);           // 16,777,216
  u16* g_ws  = (u16*)(ws + 69861632);           // 16,777,216 -> ends 86,638,848

  hipLaunchKernelGGL(k_sniff, dim3(1), dim3(64), 0, stream,
                     (const unsigned int*)msa, flag);
  hipLaunchKernelGGL(k_transpose, dim3(1280), dim3(256), 0, stream,
                     wq, wk, wv, wg, wo, flag, Wt, wot);
  hipLaunchKernelGGL(k_pair_z, dim3(4096), dim3(256), 0, stream,
                     pair, png, pnb, w2d, flag, z);
  hipLaunchKernelGGL(k_msa_ln, dim3(8192), dim3(256), 0, stream,
                     msa, qng, qnb, flag, m_bf);
  hipLaunchKernelGGL(k_qkvg, dim3(256, 8), dim3(256), 0, stream,
                     m_bf, Wt, bg, flag, q_ws, k_ws, v_ws, g_ws);
  hipLaunchKernelGGL(k_attn, dim3(1024), dim3(256), 0, stream,
                     q_ws, k_ws, v_ws, z, mask, g_ws, flag, og_ws);
  hipLaunchKernelGGL(k_outproj, dim3(256, 2), dim3(256), 0, stream,
                     og_ws, wot, bo, flag, d_out);
}

// Round 5
// 303.335 us; speedup vs baseline: 1.4582x; 1.0307x over previous
//
#include <hip/hip_runtime.h>

typedef unsigned short u16;
typedef __attribute__((ext_vector_type(8))) short bf16x8;
typedef __attribute__((ext_vector_type(4))) float f32x4;

__device__ __forceinline__ float bf2f(u16 u){
  union { unsigned int i; float f; } v; v.i = ((unsigned int)u) << 16; return v.f;
}
__device__ __forceinline__ u16 f2bf(float f){
  union { float f; unsigned int i; } v; v.f = f;
  unsigned int i = v.i;
  return (u16)((i + 0x7fffu + ((i >> 16) & 1u)) >> 16);
}
__device__ __forceinline__ float ldin(const void* p, int i, int f){
  return f ? ((const float*)p)[i] : bf2f(((const u16*)p)[i]);
}
__device__ __forceinline__ bf16x8 pack8(const float* v){
  union { bf16x8 v8; u16 h[8]; } u;
  #pragma unroll
  for (int j = 0; j < 8; ++j) u.h[j] = f2bf(v[j]);
  return u.v8;
}
// async global->LDS, 16B per lane; LDS dest = wave-uniform base + lane*16
__device__ __forceinline__ void gload16(const u16* g, u16* l){
  __builtin_amdgcn_global_load_lds(
      (const __attribute__((address_space(1))) void*)g,
      (__attribute__((address_space(3))) void*)l, 16, 0, 0);
}

// ---------------------------------------------------------------------------
// Kernel S: sniff input dtype from msa_act's first 256 words.
// ---------------------------------------------------------------------------
__global__ void k_sniff(const unsigned int* __restrict__ msa_w, int* __restrict__ flag)
{
  int lane = threadIdx.x & 63;
  int lo0 = 0, expok = 0;
  #pragma unroll
  for (int j = 0; j < 4; ++j) {
    unsigned int w = msa_w[lane * 4 + j];
    if ((w & 0xffffu) == 0u) lo0++;
    unsigned int e = (w >> 7) & 0xffu;
    if (e >= 110u && e <= 140u) expok++;
  }
  #pragma unroll
  for (int off = 1; off < 64; off <<= 1) {
    lo0   += __shfl_xor(lo0,   off, 64);
    expok += __shfl_xor(expok, off, 64);
  }
  if (lane == 0 && blockIdx.x == 0)
    *flag = (lo0 > 200) ? 1 : ((expok > 200) ? 0 : 1);
}

// ---------------------------------------------------------------------------
// Kernel 0: transpose the 5 weight matrices into bf16.
// ---------------------------------------------------------------------------
__global__ __launch_bounds__(256) void k_transpose(
    const void* __restrict__ wq, const void* __restrict__ wk,
    const void* __restrict__ wv, const void* __restrict__ wg,
    const void* __restrict__ wo, const int* __restrict__ flagp,
    u16* __restrict__ Wt, u16* __restrict__ wot)
{
  const int flag = *flagp;
  int idx = blockIdx.x * 256 + threadIdx.x;     // 0..327679
  int mat = idx >> 16;
  int col = (idx >> 8) & 255;
  int c   = idx & 255;
  const void* src = (mat == 0) ? wq : (mat == 1) ? wk : (mat == 2) ? wv
                  : (mat == 3) ? wg : wo;
  u16 v = f2bf(ldin(src, c * 256 + col, flag));
  if (idx < 262144) Wt[idx] = v;
  else              wot[idx - 262144] = v;
}

// ---------------------------------------------------------------------------
// Kernel 1: pair LayerNorm + z[h][q*256+k] via MFMA. Block = 64 rows.
// ---------------------------------------------------------------------------
__global__ __launch_bounds__(256) void k_pair_z(
    const void* __restrict__ pair, const void* __restrict__ png,
    const void* __restrict__ pnb, const void* __restrict__ w2d,
    const int* __restrict__ flagp, float* __restrict__ z)
{
  __shared__ u16 As[64 * 136];
  __shared__ u16 Bs[16 * 136];
  const int flag = *flagp;
  const int t = threadIdx.x, lane = t & 63, wave = t >> 6;
  const int g = lane >> 4, l15 = lane & 15;
  const int rowBase = blockIdx.x * 64;          // of 65536 (q*256+k)

  if (t < 128) {
    #pragma unroll
    for (int n = 0; n < 16; ++n)
      Bs[n * 136 + t] = (n < 8) ? f2bf(ldin(w2d, t * 8 + n, flag)) : (u16)0;
  }
  {
    int lrow = t >> 2, cb = (t & 3) * 32;
    int base = (rowBase + lrow) * 128 + cb;
    float x[32];
    if (flag) {
      const float* p = (const float*)pair + base;
      #pragma unroll
      for (int j = 0; j < 8; ++j) {
        float4 f4 = *(const float4*)(p + 4 * j);
        x[4*j] = f4.x; x[4*j+1] = f4.y; x[4*j+2] = f4.z; x[4*j+3] = f4.w;
      }
    } else {
      const u16* p = (const u16*)pair + base;
      #pragma unroll
      for (int j = 0; j < 4; ++j) {
        uint4 u = *(const uint4*)(p + 8 * j);
        const u16* h = (const u16*)&u;
        #pragma unroll
        for (int e = 0; e < 8; ++e) x[8*j+e] = bf2f(h[e]);
      }
    }
    float s = 0.f, sq = 0.f;
    #pragma unroll
    for (int j = 0; j < 32; ++j) { s += x[j]; sq += x[j] * x[j]; }
    s  += __shfl_xor(s, 1, 64);  s  += __shfl_xor(s, 2, 64);
    sq += __shfl_xor(sq, 1, 64); sq += __shfl_xor(sq, 2, 64);
    float mu = s * (1.f / 128.f);
    float var = sq * (1.f / 128.f) - mu * mu;
    float rs = rsqrtf(var + 1e-5f);
    u16 o[32];
    #pragma unroll
    for (int j = 0; j < 32; ++j) {
      int c = cb + j;
      o[j] = f2bf((x[j] - mu) * rs * ldin(png, c, flag) + ldin(pnb, c, flag));
    }
    u16* dst = As + lrow * 136 + cb;
    #pragma unroll
    for (int j = 0; j < 4; ++j)
      *(uint4*)(dst + 8 * j) = *(const uint4*)(o + 8 * j);
  }
  __syncthreads();

  f32x4 accz = {0.f, 0.f, 0.f, 0.f};
  #pragma unroll
  for (int kb = 0; kb < 4; ++kb) {
    bf16x8 a = *(const bf16x8*)(As + (wave * 16 + l15) * 136 + kb * 32 + g * 8);
    bf16x8 b = *(const bf16x8*)(Bs + l15 * 136 + kb * 32 + g * 8);
    accz = __builtin_amdgcn_mfma_f32_16x16x32_bf16(a, b, accz, 0, 0, 0);
  }
  if (l15 < 8) {
    #pragma unroll
    for (int r = 0; r < 4; ++r)
      z[l15 * 65536 + rowBase + wave * 16 + g * 4 + r] = accz[r];
  }
}

// ---------------------------------------------------------------------------
// Kernel 2: msa LayerNorm fully applied -> m_bf16.
// ---------------------------------------------------------------------------
__global__ __launch_bounds__(256) void k_msa_ln(
    const void* __restrict__ msa, const void* __restrict__ qng,
    const void* __restrict__ qnb, const int* __restrict__ flagp,
    u16* __restrict__ m_bf)
{
  const int flag = *flagp;
  int wave = threadIdx.x >> 6, lane = threadIdx.x & 63;
  int row = blockIdx.x * 4 + wave;              // 0..32767
  float x[4];
  if (flag) {
    float4 f4 = *((const float4*)msa + row * 64 + lane);
    x[0]=f4.x; x[1]=f4.y; x[2]=f4.z; x[3]=f4.w;
  } else {
    uint2 u = *((const uint2*)msa + row * 64 + lane);
    const u16* h = (const u16*)&u;
    #pragma unroll
    for (int j = 0; j < 4; ++j) x[j] = bf2f(h[j]);
  }
  float s = 0.f, sq = 0.f;
  #pragma unroll
  for (int j = 0; j < 4; ++j) { s += x[j]; sq += x[j] * x[j]; }
  #pragma unroll
  for (int off = 1; off < 64; off <<= 1) {
    s  += __shfl_xor(s,  off, 64);
    sq += __shfl_xor(sq, off, 64);
  }
  float mu = s * (1.f / 256.f);
  float var = sq * (1.f / 256.f) - mu * mu;
  float rs = rsqrtf(var + 1e-5f);
  u16 o[4];
  #pragma unroll
  for (int j = 0; j < 4; ++j) {
    int c = lane * 4 + j;
    o[j] = f2bf((x[j] - mu) * rs * ldin(qng, c, flag) + ldin(qnb, c, flag));
  }
  *((uint2*)m_bf + row * 64 + lane) = *(const uint2*)o;
}

// ---------------------------------------------------------------------------
// Kernel 3: QKVG projection GEMM, m97-style staging + coalesced epilogue via
// LDS transpose (dwordx4 stores).
// ---------------------------------------------------------------------------
__global__ __launch_bounds__(256) void k_qkvg(
    const u16* __restrict__ m_bf, const u16* __restrict__ Wt,
    const void* __restrict__ bg, const int* __restrict__ flagp,
    u16* __restrict__ q_ws, u16* __restrict__ k_ws,
    u16* __restrict__ v_ws, u16* __restrict__ g_ws)
{
  __shared__ u16 SM[64 * 136];   // union: K-loop As(4096)+Bs(4096); epi 64x136
  u16* As = SM;
  u16* Bs = SM + 4096;
  const int flag = *flagp;
  const int t = threadIdx.x, lane = t & 63, wave = t >> 6;
  const int wm = (wave >> 1) * 64, wn = (wave & 1) * 64;
  const int rowBase = blockIdx.x * 128;
  const int colBase = blockIdx.y * 128;
  const int g = lane >> 4, l15 = lane & 15;
  const int srow = wave * 32 + (lane >> 2);
  const int scol = (lane & 3) * 8;
  const u16* gA = m_bf + (rowBase + srow) * 256 + scol;
  const u16* gB = Wt   + (colBase + srow) * 256 + scol;
  u16* lA = As + wave * 32 * 32;
  u16* lB = Bs + wave * 32 * 32;

  f32x4 acc[4][4];
  f32x4 zero = {0.f, 0.f, 0.f, 0.f};
  #pragma unroll
  for (int i = 0; i < 4; ++i)
    #pragma unroll
    for (int j = 0; j < 4; ++j) acc[i][j] = zero;

  for (int kb = 0; kb < 256; kb += 32) {
    __syncthreads();
    gload16(gA + kb,            lA);
    gload16(gA + kb + 16 * 256, lA + 16 * 32);
    gload16(gB + kb,            lB);
    gload16(gB + kb + 16 * 256, lB + 16 * 32);
    __syncthreads();
    bf16x8 a[4], b[4];
    #pragma unroll
    for (int mt = 0; mt < 4; ++mt)
      a[mt] = *(const bf16x8*)(As + (wm + mt * 16 + l15) * 32 + g * 8);
    #pragma unroll
    for (int nt = 0; nt < 4; ++nt)
      b[nt] = *(const bf16x8*)(Bs + (wn + nt * 16 + l15) * 32 + g * 8);
    #pragma unroll
    for (int mt = 0; mt < 4; ++mt)
      #pragma unroll
      for (int nt = 0; nt < 4; ++nt)
        acc[mt][nt] = __builtin_amdgcn_mfma_f32_16x16x32_bf16(a[mt], b[nt], acc[mt][nt], 0, 0, 0);
  }

  const int t4 = colBase >> 8;          // 0=q 1=k 2=v 3=g
  const float scale = 0.17677669529663687f;
  const int hbase = (colBase >> 5) & 7;
  const int s_ = rowBase >> 8;
  #pragma unroll
  for (int p = 0; p < 2; ++p) {
    __syncthreads();
    if ((wave >> 1) == p) {   // waves holding rows [p*64, p*64+64)
      #pragma unroll
      for (int mt = 0; mt < 4; ++mt)
        #pragma unroll
        for (int nt = 0; nt < 4; ++nt)
          #pragma unroll
          for (int r = 0; r < 4; ++r) {
            int rr = mt * 16 + g * 4 + r;
            int cc = wn + nt * 16 + l15;
            float v = acc[mt][nt][r];
            u16 o;
            if (t4 == 0) o = f2bf(v * scale);
            else if (t4 == 3) {
              float gv = v + ldin(bg, (colBase & 255) + cc, flag);
              o = f2bf(1.0f / (1.0f + __expf(-gv)));
            } else o = f2bf(v);
            SM[rr * 136 + cc] = o;
          }
    }
    __syncthreads();
    int iibase = (rowBase & 255) + p * 64;
    if (t4 < 3) {
      u16* dst_ws = (t4 == 0) ? q_ws : (t4 == 1) ? k_ws : v_ws;
      int rr = t >> 2, dseg = t & 3;
      #pragma unroll
      for (int hl = 0; hl < 4; ++hl) {
        uint4 vd = *(const uint4*)(SM + rr * 136 + hl * 32 + dseg * 8);
        *(uint4*)(dst_ws + ((s_ * 8 + hbase + hl) * 256 + iibase + rr) * 32 + dseg * 8) = vd;
      }
    } else {
      // FIXED: full 64x128 coverage (was 64x64 -> poison gates)
      int cbase = colBase & 255;
      int rr4 = t >> 4, cseg = t & 15;
      #pragma unroll
      for (int jr = 0; jr < 4; ++jr) {
        int rr = jr * 16 + rr4;
        uint4 vd = *(const uint4*)(SM + rr * 136 + cseg * 8);
        *(uint4*)(g_ws + (s_ * 256 + iibase + rr) * 256 + cbase + cseg * 8) = vd;
      }
    }
  }
}

// ---------------------------------------------------------------------------
// Kernel 4: attention per (s,h). QK^T -> transpose S to A-layout BEFORE
// softmax, vectorized z/mask adds, 2-shuffle softmax, in-register P pack, PV.
// ---------------------------------------------------------------------------
__global__ __launch_bounds__(256) void k_attn(
    const u16* __restrict__ q_ws, const u16* __restrict__ k_ws,
    const u16* __restrict__ v_ws, const float* __restrict__ z,
    const void* __restrict__ mask, const u16* __restrict__ g_ws,
    const int* __restrict__ flagp, u16* __restrict__ og_ws)
{
  __shared__ u16 Ks[256 * 32];        // [k][d]
  __shared__ u16 Vts[32 * 264];       // [d][k]
  __shared__ float Tb[4][16 * 36];    // per-wave S-transpose buffer
  __shared__ float Mb[256];           // mask bias per key
  const int flag = *flagp;
  const int t = threadIdx.x, lane = t & 63, wave = t >> 6;
  const int sh = blockIdx.x;          // s*8+h
  const int s_ = sh >> 3, h = sh & 7;

  {
    const uint4* srcK = (const uint4*)(k_ws + sh * 8192);
    uint4* dstK = (uint4*)Ks;
    #pragma unroll
    for (int j = 0; j < 4; ++j) dstK[t + 256 * j] = srcK[t + 256 * j];
    const u16* sv = v_ws + sh * 8192 + t * 32;
    uint4 v0 = *(const uint4*)sv, v1 = *(const uint4*)(sv + 8);
    const u16* ve = (const u16*)&v0;
    const u16* vo = (const u16*)&v1;
    #pragma unroll
    for (int d = 0; d < 8; ++d) Vts[d * 264 + t] = ve[d];
    #pragma unroll
    for (int d = 0; d < 8; ++d) Vts[(8 + d) * 264 + t] = vo[d];
    const u16* sv2 = sv + 16;
    uint4 v2 = *(const uint4*)sv2, v3 = *(const uint4*)(sv2 + 8);
    const u16* ve2 = (const u16*)&v2;
    const u16* vo2 = (const u16*)&v3;
    #pragma unroll
    for (int d = 0; d < 8; ++d) Vts[(16 + d) * 264 + t] = ve2[d];
    #pragma unroll
    for (int d = 0; d < 8; ++d) Vts[(24 + d) * 264 + t] = vo2[d];
    Mb[t] = 1e9f * (ldin(mask, s_ * 256 + t, flag) - 1.0f);
  }
  __syncthreads();

  const int g = lane >> 4, l15 = lane & 15;
  const u16* qb = q_ws + sh * 8192;
  float* Tw = &Tb[wave][0];
  f32x4 zero = {0.f, 0.f, 0.f, 0.f};

  for (int qt = 0; qt < 4; ++qt) {
    const int qbase = wave * 64 + qt * 16;
    bf16x8 aq = *(const bf16x8*)(qb + (qbase + l15) * 32 + g * 8);
    f32x4 S[16];
    #pragma unroll
    for (int kt = 0; kt < 16; ++kt) {
      bf16x8 bk = *(const bf16x8*)(Ks + (kt * 16 + l15) * 32 + g * 8);
      S[kt] = __builtin_amdgcn_mfma_f32_16x16x32_bf16(aq, bk, zero, 0, 0, 0);
    }
    float L[8][8];
    const float* zr = z + h * 65536 + (qbase + l15) * 256;
    #pragma unroll
    for (int kc = 0; kc < 8; ++kc) {
      asm volatile("s_waitcnt lgkmcnt(0)" ::: "memory");
      #pragma unroll
      for (int half = 0; half < 2; ++half)
        #pragma unroll
        for (int r = 0; r < 4; ++r)
          Tw[(g * 4 + r) * 36 + half * 16 + l15] = S[kc * 2 + half][r];
      asm volatile("s_waitcnt lgkmcnt(0)" ::: "memory");
      float4 t0 = *(const float4*)(Tw + l15 * 36 + g * 8);
      float4 t1 = *(const float4*)(Tw + l15 * 36 + g * 8 + 4);
      float4 m0 = *(const float4*)(Mb + kc * 32 + g * 8);
      float4 m1 = *(const float4*)(Mb + kc * 32 + g * 8 + 4);
      float4 z0 = *(const float4*)(zr + kc * 32 + g * 8);
      float4 z1 = *(const float4*)(zr + kc * 32 + g * 8 + 4);
      L[kc][0] = t0.x + m0.x + z0.x;  L[kc][1] = t0.y + m0.y + z0.y;
      L[kc][2] = t0.z + m0.z + z0.z;  L[kc][3] = t0.w + m0.w + z0.w;
      L[kc][4] = t1.x + m1.x + z1.x;  L[kc][5] = t1.y + m1.y + z1.y;
      L[kc][6] = t1.z + m1.z + z1.z;  L[kc][7] = t1.w + m1.w + z1.w;
    }
    float mx = -1e30f;
    #pragma unroll
    for (int kc = 0; kc < 8; ++kc)
      #pragma unroll
      for (int j = 0; j < 8; ++j) mx = fmaxf(mx, L[kc][j]);
    mx = fmaxf(mx, __shfl_xor(mx, 16, 64));
    mx = fmaxf(mx, __shfl_xor(mx, 32, 64));
    float sm = 0.f;
    #pragma unroll
    for (int kc = 0; kc < 8; ++kc)
      #pragma unroll
      for (int j = 0; j < 8; ++j) {
        float p = __expf(L[kc][j] - mx);
        L[kc][j] = p;
        sm += p;
      }
    sm += __shfl_xor(sm, 16, 64);
    sm += __shfl_xor(sm, 32, 64);
    f32x4 O0 = zero, O1 = zero;
    #pragma unroll
    for (int kc = 0; kc < 8; ++kc) {
      bf16x8 ap  = pack8(&L[kc][0]);
      bf16x8 bv0 = *(const bf16x8*)(Vts + l15 * 264 + kc * 32 + g * 8);
      bf16x8 bv1 = *(const bf16x8*)(Vts + (16 + l15) * 264 + kc * 32 + g * 8);
      O0 = __builtin_amdgcn_mfma_f32_16x16x32_bf16(ap, bv0, O0, 0, 0, 0);
      O1 = __builtin_amdgcn_mfma_f32_16x16x32_bf16(ap, bv1, O1, 0, 0, 0);
    }
    #pragma unroll
    for (int r = 0; r < 4; ++r) {
      float smr = __shfl(sm, g * 4 + r, 64);
      float inv = 1.0f / smr;
      int qq = qbase + g * 4 + r;
      int base = (s_ * 256 + qq) * 256 + h * 32;
      float o0 = O0[r] * inv * bf2f(g_ws[base + l15]);
      float o1 = O1[r] * inv * bf2f(g_ws[base + 16 + l15]);
      og_ws[base + l15]      = f2bf(o0);
      og_ws[base + 16 + l15] = f2bf(o1);
    }
  }
}

// ---------------------------------------------------------------------------
// Kernel 5: output projection GEMM. M=32768, N=256, K=256. +bo.
// ---------------------------------------------------------------------------
__global__ __launch_bounds__(256) void k_outproj(
    const u16* __restrict__ og, const u16* __restrict__ wot,
    const void* __restrict__ bo, const int* __restrict__ flagp,
    void* __restrict__ outv)
{
  __shared__ u16 As[128 * 32];
  __shared__ u16 Bs[128 * 32];
  const int flag = *flagp;
  const int t = threadIdx.x, lane = t & 63, wave = t >> 6;
  const int wm = (wave >> 1) * 64, wn = (wave & 1) * 64;
  const int rowBase = blockIdx.x * 128;
  const int colBase = blockIdx.y * 128;
  const int g = lane >> 4, l15 = lane & 15;
  const int srow = wave * 32 + (lane >> 2);
  const int scol = (lane & 3) * 8;
  const u16* gA = og  + (rowBase + srow) * 256 + scol;
  const u16* gB = wot + (colBase + srow) * 256 + scol;
  u16* lA = As + wave * 32 * 32;
  u16* lB = Bs + wave * 32 * 32;

  f32x4 acc[4][4];
  f32x4 zero = {0.f, 0.f, 0.f, 0.f};
  #pragma unroll
  for (int i = 0; i < 4; ++i)
    #pragma unroll
    for (int j = 0; j < 4; ++j) acc[i][j] = zero;

  for (int kb = 0; kb < 256; kb += 32) {
    __syncthreads();
    gload16(gA + kb,            lA);
    gload16(gA + kb + 16 * 256, lA + 16 * 32);
    gload16(gB + kb,            lB);
    gload16(gB + kb + 16 * 256, lB + 16 * 32);
    __syncthreads();
    bf16x8 a[4], b[4];
    #pragma unroll
    for (int mt = 0; mt < 4; ++mt)
      a[mt] = *(const bf16x8*)(As + (wm + mt * 16 + l15) * 32 + g * 8);
    #pragma unroll
    for (int nt = 0; nt < 4; ++nt)
      b[nt] = *(const bf16x8*)(Bs + (wn + nt * 16 + l15) * 32 + g * 8);
    #pragma unroll
    for (int mt = 0; mt < 4; ++mt)
      #pragma unroll
      for (int nt = 0; nt < 4; ++nt)
        acc[mt][nt] = __builtin_amdgcn_mfma_f32_16x16x32_bf16(a[mt], b[nt], acc[mt][nt], 0, 0, 0);
  }
  #pragma unroll
  for (int mt = 0; mt < 4; ++mt)
    #pragma unroll
    for (int nt = 0; nt < 4; ++nt)
      #pragma unroll
      for (int r = 0; r < 4; ++r) {
        int row = rowBase + wm + mt * 16 + g * 4 + r;
        int col = colBase + wn + nt * 16 + l15;
        float val = acc[mt][nt][r] + ldin(bo, col, flag);
        if (flag) ((float*)outv)[row * 256 + col] = val;
        else      ((u16*)outv)[row * 256 + col]   = f2bf(val);
      }
}

// ---------------------------------------------------------------------------
extern "C" void kernel_launch(void* const* d_in, const int* in_sizes, int n_in,
                              void* d_out, int out_size, void* d_ws, size_t ws_size,
                              hipStream_t stream)
{
  const void* msa  = d_in[0];
  const void* pair = d_in[1];
  const void* mask = d_in[2];
  const void* qng  = d_in[3];
  const void* qnb  = d_in[4];
  const void* png  = d_in[5];
  const void* pnb  = d_in[6];
  const void* w2d  = d_in[7];
  const void* wq   = d_in[8];
  const void* wk   = d_in[9];
  const void* wv   = d_in[10];
  const void* wg   = d_in[11];
  const void* bg   = d_in[12];
  const void* wo   = d_in[13];
  const void* bo   = d_in[14];

  char* ws = (char*)d_ws;
  float* z   = (float*)(ws + 0);                //  2,097,152
  u16* Wt    = (u16*)(ws + 2097152);            //    524,288
  u16* wot   = (u16*)(ws + 2621440);            //    131,072
  int* flag  = (int*)(ws + 2752512);            //        256
  u16* m_bf  = (u16*)(ws + 2752768);            // 16,777,216 (aliased w/ og_ws)
  u16* og_ws = m_bf;                            //   (m_bf dead after k_qkvg)
  u16* q_ws  = (u16*)(ws + 19529984);           // 16,777,216
  u16* k_ws  = (u16*)(ws + 36307200);           // 16,777,216
  u16* v_ws  = (u16*)(ws + 53084416);           // 16,777,216
  u16* g_ws  = (u16*)(ws + 69861632);           // 16,777,216 -> ends 86,638,848

  hipLaunchKernelGGL(k_sniff, dim3(1), dim3(64), 0, stream,
                     (const unsigned int*)msa, flag);
  hipLaunchKernelGGL(k_transpose, dim3(1280), dim3(256), 0, stream,
                     wq, wk, wv, wg, wo, flag, Wt, wot);
  hipLaunchKernelGGL(k_msa_ln, dim3(8192), dim3(256), 0, stream,
                     msa, qng, qnb, flag, m_bf);
  hipLaunchKernelGGL(k_qkvg, dim3(256, 8), dim3(256), 0, stream,
                     m_bf, Wt, bg, flag, q_ws, k_ws, v_ws, g_ws);
  hipLaunchKernelGGL(k_pair_z, dim3(1024), dim3(256), 0, stream,
                     pair, png, pnb, w2d, flag, z);
  hipLaunchKernelGGL(k_attn, dim3(1024), dim3(256), 0, stream,
                     q_ws, k_ws, v_ws, z, mask, g_ws, flag, og_ws);
  hipLaunchKernelGGL(k_outproj, dim3(256, 2), dim3(256), 0, stream,
                     og_ws, wot, bo, flag, d_out);
}